// Round 4
// baseline (486.675 us; speedup 1.0000x reference)
//
#include <hip/hip_runtime.h>

#define B_ 2
#define L_ 2048
#define S_ 2048
#define H_ 8
#define E_ 64
#define VSTRIDE 132   // u16 per vstage row (64 data u32 + 2 u32 pad); LDS total 19.5KB -> 8 blocks/CU

typedef float f32x4 __attribute__((ext_vector_type(4)));
typedef short s16x8 __attribute__((ext_vector_type(8)));
typedef unsigned int u32;
typedef unsigned short u16;
typedef unsigned long long u64;

__device__ __forceinline__ u32 bc(float f){ return __builtin_bit_cast(u32, f); }
__device__ __forceinline__ float exp2g(float x){ return __builtin_amdgcn_exp2f(x); }

// pack 8 f32 -> 8 bf16 (truncate-to-bf16 via v_perm; ample slack vs threshold)
__device__ __forceinline__ s16x8 pack8(f32x4 a, f32x4 b){
  union { s16x8 v; u32 w[4]; } r;
  r.w[0] = __builtin_amdgcn_perm(bc(a[1]), bc(a[0]), 0x07060302u);
  r.w[1] = __builtin_amdgcn_perm(bc(a[3]), bc(a[2]), 0x07060302u);
  r.w[2] = __builtin_amdgcn_perm(bc(b[1]), bc(b[0]), 0x07060302u);
  r.w[3] = __builtin_amdgcn_perm(bc(b[3]), bc(b[2]), 0x07060302u);
  return r.v;
}

__device__ __forceinline__ void loadK2(const float* kr, s16x8& f0, s16x8& f1){
  f32x4 a0 = *(const f32x4*)(kr);
  f32x4 a1 = *(const f32x4*)(kr + 4);
  f32x4 b0 = *(const f32x4*)(kr + 32);
  f32x4 b1 = *(const f32x4*)(kr + 36);
  f0 = pack8(a0, a1);
  f1 = pack8(b0, b1);
}

// 256 thr, min 8 blocks/CU -> VGPR cap 64 (kernel held TWO tiles in 64 before; one tile has slack)
__launch_bounds__(256, 8)
__global__ void attn_kernel(const float* __restrict__ Q,
                            const float* __restrict__ K,
                            const float* __restrict__ V,
                            const int* __restrict__ maskK,
                            const int* __restrict__ maskQ,
                            const int* __restrict__ causal_p,
                            float* __restrict__ outV,
                            float* __restrict__ outA,
                            float* __restrict__ outEnt)
{
  // LDS 19.5 KB total; vstage is wave-private by construction (no barriers in sweep 2)
  __shared__ __align__(16) u16 vstage[64 * VSTRIDE];   // V tile [e][j] bf16, swizzled; reused as Ubuf
  __shared__ float lsum[4][16];
  __shared__ float tsum[4][16];
  __shared__ float recipS[16];
  __shared__ __align__(8) unsigned char mkb[2048];

  const int tid  = threadIdx.x;
  const int lane = tid & 63;
  const int wv   = tid >> 6;
  const int quad = lane >> 4;
  const int l15  = lane & 15;
  // K-fragment row permutation: MFMA "A-row" i holds K row perm(i)=(i>>2)*8+(i&3)
  // so S^T output reg r at quad q is j = j0 + q*8 + r  (second frag: +4)
  const int permrow = ((l15 >> 2) << 3) | (l15 & 3);

  // ---- XCD-aware decode: block n -> XCD n&7; each XCD owns 2 (b,h) slices.
  // One 16-row tile per block; heavy tiles (large i0) first for causal load balance.
  const int n   = blockIdx.x;          // 0..2047
  const int s   = n >> 3;              // 0..255
  const int bh  = ((n & 7) << 1) | (s >> 7);
  const int b   = bh >> 3;
  const int h   = bh & 7;
  const int i0  = (127 - (s & 127)) << 4;

  const int causal = causal_p[0] != 0;
  const int imax   = causal ? (i0 + 15) : (S_ - 1);
  const int nsup   = (imax >> 7) + 1;

  // ---- stage key-miss mask bytes ----
  {
    const int* mk = maskK + b * S_ + tid * 8;
    u32 w0 = (u32)(mk[0]!=0) | ((u32)(mk[1]!=0)<<8) | ((u32)(mk[2]!=0)<<16) | ((u32)(mk[3]!=0)<<24);
    u32 w1 = (u32)(mk[4]!=0) | ((u32)(mk[5]!=0)<<8) | ((u32)(mk[6]!=0)<<16) | ((u32)(mk[7]!=0)<<24);
    ((uint2*)mkb)[tid] = make_uint2(w0, w1);
  }

  float* const outArow = outA + ((size_t)bh * L_ + i0) * S_;

  // ---- zero-fill causal upper triangle ----
  if (causal){
    const f32x4 z4 = {0.f, 0.f, 0.f, 0.f};
    const int jz = ((imax >> 5) + 1) << 5;
    for (int r = 0; r < 16; ++r)
      for (int c = jz + (tid << 2); c < S_; c += 1024)
        *(f32x4*)(outArow + (size_t)r * S_ + c) = z4;
  }

  // ---- Q fragments, pre-scaled by (1/sqrt(E))*log2(e) ----
  s16x8 qf0, qf1;
  {
    const float qs = 0.125f * 1.44269504f;
    const float* qa = Q + (((size_t)(b * L_ + i0 + l15)) * H_ + h) * E_;
    qf0 = pack8(*(const f32x4*)(qa + quad*8) * qs,      *(const f32x4*)(qa + quad*8 + 4) * qs);
    qf1 = pack8(*(const f32x4*)(qa + 32 + quad*8) * qs, *(const f32x4*)(qa + 32 + quad*8 + 4) * qs);
  }

  const size_t rstride = (size_t)(H_ * E_);
  const float* const Kbh = K + ((size_t)(b * S_) * H_ + h) * E_;
  const f32x4 zero4 = {0.f, 0.f, 0.f, 0.f};
  const int irow = i0 + l15;

  __syncthreads();  // mkb visible

  // ================= SWEEP 1: row sums l,t =================
  // S^T layout: lane (quad,l15) owns row l15, j = j0c + quad*8 + {0..3} (+4 in sb)
  float lacc = 0.f, tacc = 0.f;
  for (int c = wv; (c << 5) <= imax; c += 4){
    const int j0c = c << 5;
    s16x8 ka0, ka1, kb0, kb1;
    const float* krow = Kbh + (size_t)(j0c + permrow) * rstride + quad * 8;
    loadK2(krow, ka0, ka1);
    loadK2(krow + 4 * rstride, kb0, kb1);
    const int jbase = j0c + (quad << 3);
    const u64 mk8 = *(const u64*)(mkb + jbase);   // broadcast within quad groups
    const u32 mlo = (u32)mk8;
    const u32 mhi = (u32)(mk8 >> 32);
    f32x4 sa = __builtin_amdgcn_mfma_f32_16x16x32_bf16(ka0, qf0, zero4, 0, 0, 0);
    sa       = __builtin_amdgcn_mfma_f32_16x16x32_bf16(ka1, qf1, sa, 0, 0, 0);
    f32x4 sb = __builtin_amdgcn_mfma_f32_16x16x32_bf16(kb0, qf0, zero4, 0, 0, 0);
    sb       = __builtin_amdgcn_mfma_f32_16x16x32_bf16(kb1, qf1, sb, 0, 0, 0);
    const int rel = irow - jbase;
    #pragma unroll
    for (int r = 0; r < 4; ++r){
      const bool da = (((mlo >> (8*r)) & 0xffu) != 0u) || (causal && (r > rel));
      const float ea = da ? 0.f : exp2g(sa[r]);
      lacc += ea; tacc = __builtin_fmaf(ea, sa[r], tacc);
      const bool db = (((mhi >> (8*r)) & 0xffu) != 0u) || (causal && (r + 4 > rel));
      const float eb = db ? 0.f : exp2g(sb[r]);
      lacc += eb; tacc = __builtin_fmaf(eb, sb[r], tacc);
    }
  }

  // ---- reduce over quads (lane already holds full per-row partial) ----
  #pragma unroll
  for (int off = 16; off < 64; off <<= 1){
    lacc += __shfl_xor(lacc, off);  tacc += __shfl_xor(tacc, off);
  }
  if (lane < 16){
    lsum[wv][l15] = lacc;  tsum[wv][l15] = tacc;
  }
  __syncthreads();
  if (tid < 16){
    float l = lsum[0][tid] + lsum[1][tid] + lsum[2][tid] + lsum[3][tid];
    float t = (tsum[0][tid] + tsum[1][tid] + tsum[2][tid] + tsum[3][tid]) * 0.69314718f;
    const int row = i0 + tid;
    int qm = maskQ[b * L_ + row];
    float rc  = (qm != 0) ? 0.f : (1.f / l);
    float ent = (qm != 0) ? 0.f : (__logf(l) - t / l);
    recipS[tid] = rc;
    outEnt[(size_t)bh * L_ + row] = ent;
  }
  __syncthreads();

  const float rq = recipS[l15];

  // ================= SWEEP 2: A out + PV (barrier-free) =================
  f32x4 uacc[4];
  #pragma unroll
  for (int et = 0; et < 4; ++et) uacc[et] = (f32x4)0.f;

  for (int sp = 0; sp < nsup; ++sp){
    const int j0c = (sp << 7) + (wv << 5);
    if (j0c > imax) break;   // monotone in sp; uniform per wave

    // ---- stage this wave's V[j0c..j0c+32][:] -> vstage bf16 [e][j], granule-rotated ----
    // wave-private: jp = tid>>2 spans [wv*16, wv*16+16) -> j in [wv*32, wv*32+32)
    {
      const int jp = tid >> 2;
      const int a  = tid & 3;
      const int e0 = a << 4;
      const float* v0 = V + (((size_t)(b * S_ + (sp << 7) + 2 * jp)) * H_ + h) * E_ + e0;
      const float* v1 = v0 + H_ * E_;
      f32x4 x0 = *(const f32x4*)(v0);
      f32x4 x1 = *(const f32x4*)(v0 + 4);
      f32x4 x2 = *(const f32x4*)(v0 + 8);
      f32x4 x3 = *(const f32x4*)(v0 + 12);
      f32x4 y0 = *(const f32x4*)(v1);
      f32x4 y1 = *(const f32x4*)(v1 + 4);
      f32x4 y2 = *(const f32x4*)(v1 + 8);
      f32x4 y3 = *(const f32x4*)(v1 + 12);
      const int colsw = ((((jp >> 2) + (a << 2)) & 15) << 2) | (jp & 3);
      u32* vsw = (u32*)vstage;
      #pragma unroll
      for (int k = 0; k < 4; ++k){
        vsw[(e0 + k     ) * (VSTRIDE/2) + colsw] = __builtin_amdgcn_perm(bc(y0[k]), bc(x0[k]), 0x07060302u);
        vsw[(e0 + 4 + k ) * (VSTRIDE/2) + colsw] = __builtin_amdgcn_perm(bc(y1[k]), bc(x1[k]), 0x07060302u);
        vsw[(e0 + 8 + k ) * (VSTRIDE/2) + colsw] = __builtin_amdgcn_perm(bc(y2[k]), bc(x2[k]), 0x07060302u);
        vsw[(e0 + 12 + k) * (VSTRIDE/2) + colsw] = __builtin_amdgcn_perm(bc(y3[k]), bc(x3[k]), 0x07060302u);
      }
    }

    s16x8 ka0, ka1, kb0, kb1;
    const float* krow = Kbh + (size_t)(j0c + permrow) * rstride + quad * 8;
    loadK2(krow, ka0, ka1);
    loadK2(krow + 4 * rstride, kb0, kb1);
    const int jbase = j0c + (quad << 3);
    const u64 mk8 = *(const u64*)(mkb + jbase);
    const u32 mlo = (u32)mk8;
    const u32 mhi = (u32)(mk8 >> 32);

    // ---- QK, exp, A-store ----
    f32x4 sa = __builtin_amdgcn_mfma_f32_16x16x32_bf16(ka0, qf0, zero4, 0, 0, 0);
    sa       = __builtin_amdgcn_mfma_f32_16x16x32_bf16(ka1, qf1, sa, 0, 0, 0);
    f32x4 sb = __builtin_amdgcn_mfma_f32_16x16x32_bf16(kb0, qf0, zero4, 0, 0, 0);
    sb       = __builtin_amdgcn_mfma_f32_16x16x32_bf16(kb1, qf1, sb, 0, 0, 0);
    const int rel = irow - jbase;
    f32x4 ea, eb;
    #pragma unroll
    for (int r = 0; r < 4; ++r){
      const bool da = (((mlo >> (8*r)) & 0xffu) != 0u) || (causal && (r > rel));
      ea[r] = da ? 0.f : exp2g(sa[r]);
      const bool db = (((mhi >> (8*r)) & 0xffu) != 0u) || (causal && (r + 4 > rel));
      eb[r] = db ? 0.f : exp2g(sb[r]);
    }
    *(f32x4*)(outArow + (size_t)l15 * S_ + jbase)     = ea * rq;
    *(f32x4*)(outArow + (size_t)l15 * S_ + jbase + 4) = eb * rq;
    const s16x8 pf = pack8(ea, eb);   // direct A-operand: j = quad*8 + {0..7}

    // ---- PV ----
    #pragma unroll
    for (int et = 0; et < 4; ++et){
      const int gq = ((wv << 2) + quad + (et << 2)) & 15;
      const s16x8 vf = *(const s16x8*)(vstage + (et * 16 + l15) * VSTRIDE + gq * 8);
      uacc[et] = __builtin_amdgcn_mfma_f32_16x16x32_bf16(pf, vf, uacc[et], 0, 0, 0);
    }
  }

  // ================= epilogue: V output =================
  float* Ubuf = (float*)vstage;   // 64 rows x 64 cols = 16KB <= vstage 16.9KB
  __syncthreads();
  #pragma unroll
  for (int et = 0; et < 4; ++et)
    #pragma unroll
    for (int r = 0; r < 4; ++r)
      Ubuf[(wv * 16 + (quad << 2) + r) * 64 + et * 16 + l15] = uacc[et][r];
  __syncthreads();
  {
    const int i  = tid >> 4;
    const int e4 = (tid & 15) << 2;
    f32x4 s0 = *(const f32x4*)(Ubuf + (0 * 16 + i) * 64 + e4);
    f32x4 s1 = *(const f32x4*)(Ubuf + (1 * 16 + i) * 64 + e4);
    f32x4 s2 = *(const f32x4*)(Ubuf + (2 * 16 + i) * 64 + e4);
    f32x4 s3 = *(const f32x4*)(Ubuf + (3 * 16 + i) * 64 + e4);
    f32x4 vout = (s0 + s1 + s2 + s3) * recipS[i];
    *(f32x4*)(outV + (((size_t)(b * L_ + i0 + i)) * H_ + h) * E_ + e4) = vout;
  }
}

extern "C" void kernel_launch(void* const* d_in, const int* in_sizes, int n_in,
                              void* d_out, int out_size, void* d_ws, size_t ws_size,
                              hipStream_t stream){
  const float* Q  = (const float*)d_in[0];
  const float* K  = (const float*)d_in[1];
  const float* V  = (const float*)d_in[2];
  const int* mk   = (const int*)d_in[3];
  const int* mq   = (const int*)d_in[4];
  const int* cm   = (const int*)d_in[6];

  float* outV   = (float*)d_out;
  float* outA   = outV + (size_t)B_ * L_ * H_ * E_;
  float* outEnt = outA + (size_t)B_ * H_ * L_ * S_;

  attn_kernel<<<dim3(2048), 256, 0, stream>>>(Q, K, V, mk, mq, cm, outV, outA, outEnt);
}

// Round 5
// 346.514 us; speedup vs baseline: 1.4045x; 1.4045x over previous
//
#include <hip/hip_runtime.h>

#define B_ 2
#define L_ 2048
#define S_ 2048
#define H_ 8
#define E_ 64
#define VSTRIDE 136   // u16 per vstage row (64 data u32 + 4 u32 pad)
#define NKV 2097152   // B*S*H*E elements

typedef float f32x4 __attribute__((ext_vector_type(4)));
typedef short s16x8 __attribute__((ext_vector_type(8)));
typedef unsigned int u32;
typedef u32 u32x4 __attribute__((ext_vector_type(4)));
typedef unsigned short u16;
typedef unsigned long long u64;

__device__ __forceinline__ u32 bc(float f){ return __builtin_bit_cast(u32, f); }
__device__ __forceinline__ float exp2g(float x){ return __builtin_amdgcn_exp2f(x); }

// pack 8 f32 -> 8 bf16 (truncate-to-bf16 via v_perm; ample slack vs threshold)
__device__ __forceinline__ s16x8 pack8(f32x4 a, f32x4 b){
  union { s16x8 v; u32 w[4]; } r;
  r.w[0] = __builtin_amdgcn_perm(bc(a[1]), bc(a[0]), 0x07060302u);
  r.w[1] = __builtin_amdgcn_perm(bc(a[3]), bc(a[2]), 0x07060302u);
  r.w[2] = __builtin_amdgcn_perm(bc(b[1]), bc(b[0]), 0x07060302u);
  r.w[3] = __builtin_amdgcn_perm(bc(b[3]), bc(b[2]), 0x07060302u);
  return r.v;
}

// one-time K/V f32 -> bf16 cast (same truncation pack8 did in-kernel: bit-identical results)
__launch_bounds__(256)
__global__ void cast_kv_kernel(const float* __restrict__ K, const float* __restrict__ V,
                               u16* __restrict__ Kb, u16* __restrict__ Vb){
  const size_t o = ((size_t)blockIdx.x * 256 + threadIdx.x) * 8;
  f32x4 k0 = *(const f32x4*)(K + o);
  f32x4 k1 = *(const f32x4*)(K + o + 4);
  f32x4 v0 = *(const f32x4*)(V + o);
  f32x4 v1 = *(const f32x4*)(V + o + 4);
  *(s16x8*)(Kb + o) = pack8(k0, k1);
  *(s16x8*)(Vb + o) = pack8(v0, v1);
}

__launch_bounds__(256, 4)
__global__ void attn_kernel(const float* __restrict__ Q,
                            const u16* __restrict__ Kb,
                            const u16* __restrict__ Vb,
                            const int* __restrict__ maskK,
                            const int* __restrict__ maskQ,
                            const int* __restrict__ causal_p,
                            float* __restrict__ outV,
                            float* __restrict__ outA,
                            float* __restrict__ outEnt)
{
  // LDS ~20.6 KB; vstage is wave-private by construction (no barriers in sweep 2)
  __shared__ __align__(16) u16 vstage[64 * VSTRIDE];   // V tile [e][j] bf16, swizzled; reused as Ubuf
  __shared__ float lsum[4][32];
  __shared__ float tsum[4][32];
  __shared__ float recipS[32];
  __shared__ __align__(8) unsigned char mkb[2048];

  const int tid  = threadIdx.x;
  const int lane = tid & 63;
  const int wv   = tid >> 6;
  const int quad = lane >> 4;
  const int l15  = lane & 15;
  // K-fragment row permutation: MFMA "A-row" i holds K row perm(i)=(i>>2)*8+(i&3)
  // so S^T output reg r at quad q is j = j0 + q*8 + r  (second frag: +4)
  const int permrow = ((l15 >> 2) << 3) | (l15 & 3);

  // ---- XCD-aware decode: block n -> XCD n&7; each XCD owns 2 (b,h) slices ----
  const int n   = blockIdx.x;
  const int s   = n >> 3;
  const int bh  = ((n & 7) << 1) | (s >> 6);
  const int b   = bh >> 3;
  const int h   = bh & 7;
  const int iA  = (s & 63) << 4;      // light tile
  const int iB  = 2032 - iA;          // heavy tile; iA+iB const -> balanced blocks

  const int causal = causal_p[0] != 0;
  const int imaxA  = causal ? (iA + 15) : (S_ - 1);
  const int imaxB  = causal ? (iB + 15) : (S_ - 1);
  const int nsup   = (imaxB >> 7) + 1;

  // ---- stage key-miss mask bytes ----
  {
    const int* mk = maskK + b * S_ + tid * 8;
    u32 w0 = (u32)(mk[0]!=0) | ((u32)(mk[1]!=0)<<8) | ((u32)(mk[2]!=0)<<16) | ((u32)(mk[3]!=0)<<24);
    u32 w1 = (u32)(mk[4]!=0) | ((u32)(mk[5]!=0)<<8) | ((u32)(mk[6]!=0)<<16) | ((u32)(mk[7]!=0)<<24);
    ((uint2*)mkb)[tid] = make_uint2(w0, w1);
  }

  float* const outArowA = outA + ((size_t)bh * L_ + iA) * S_;
  float* const outArowB = outA + ((size_t)bh * L_ + iB) * S_;

  // ---- zero-fill causal upper triangles ----
  if (causal){
    const f32x4 z4 = {0.f, 0.f, 0.f, 0.f};
    const int jzA = ((imaxA >> 5) + 1) << 5;
    for (int r = 0; r < 16; ++r)
      for (int c = jzA + (tid << 2); c < S_; c += 1024)
        *(f32x4*)(outArowA + (size_t)r * S_ + c) = z4;
    const int jzB = ((imaxB >> 5) + 1) << 5;
    for (int r = 0; r < 16; ++r)
      for (int c = jzB + (tid << 2); c < S_; c += 1024)
        *(f32x4*)(outArowB + (size_t)r * S_ + c) = z4;
  }

  // ---- Q fragments for both tiles, pre-scaled by (1/sqrt(E))*log2(e) ----
  s16x8 qfA0, qfA1, qfB0, qfB1;
  {
    const float qs = 0.125f * 1.44269504f;
    const float* qa = Q + (((size_t)(b * L_ + iA + l15)) * H_ + h) * E_;
    const float* qb = Q + (((size_t)(b * L_ + iB + l15)) * H_ + h) * E_;
    qfA0 = pack8(*(const f32x4*)(qa + quad*8) * qs,      *(const f32x4*)(qa + quad*8 + 4) * qs);
    qfA1 = pack8(*(const f32x4*)(qa + 32 + quad*8) * qs, *(const f32x4*)(qa + 32 + quad*8 + 4) * qs);
    qfB0 = pack8(*(const f32x4*)(qb + quad*8) * qs,      *(const f32x4*)(qb + quad*8 + 4) * qs);
    qfB1 = pack8(*(const f32x4*)(qb + 32 + quad*8) * qs, *(const f32x4*)(qb + 32 + quad*8 + 4) * qs);
  }

  const int rstride = H_ * E_;   // u16 units (512)
  const u16* const Kbh = Kb + ((size_t)(b * S_) * H_ + h) * E_;
  const u16* const Vbh = Vb + ((size_t)(b * S_) * H_ + h) * E_;
  const f32x4 zero4 = {0.f, 0.f, 0.f, 0.f};
  const int irowA = iA + l15;
  const int irowB = iB + l15;

  __syncthreads();  // mkb visible

  // ================= SWEEP 1: row sums l,t for both tiles (shared bf16 K loads) =================
  // S^T layout: lane (quad,l15) owns row l15, j = j0c + quad*8 + {0..3} (+4 in sb)
  float lA = 0.f, tA = 0.f, lB = 0.f, tB = 0.f;
  for (int c = wv; (c << 5) <= imaxB; c += 4){
    const int j0c = c << 5;
    const u16* krow = Kbh + (size_t)(j0c + permrow) * rstride + quad * 8;
    const s16x8 ka0 = *(const s16x8*)(krow);
    const s16x8 ka1 = *(const s16x8*)(krow + 32);
    const s16x8 kb0 = *(const s16x8*)(krow + 4 * rstride);
    const s16x8 kb1 = *(const s16x8*)(krow + 4 * rstride + 32);
    const int jbase = j0c + (quad << 3);
    const u64 mk8 = *(const u64*)(mkb + jbase);   // broadcast within quad groups
    const u32 mlo = (u32)mk8;
    const u32 mhi = (u32)(mk8 >> 32);
    {
      f32x4 sa = __builtin_amdgcn_mfma_f32_16x16x32_bf16(ka0, qfB0, zero4, 0, 0, 0);
      sa       = __builtin_amdgcn_mfma_f32_16x16x32_bf16(ka1, qfB1, sa, 0, 0, 0);
      f32x4 sb = __builtin_amdgcn_mfma_f32_16x16x32_bf16(kb0, qfB0, zero4, 0, 0, 0);
      sb       = __builtin_amdgcn_mfma_f32_16x16x32_bf16(kb1, qfB1, sb, 0, 0, 0);
      const int rel = irowB - jbase;
      #pragma unroll
      for (int r = 0; r < 4; ++r){
        const bool da = (((mlo >> (8*r)) & 0xffu) != 0u) || (causal && (r > rel));
        const float ea = da ? 0.f : exp2g(sa[r]);
        lB += ea; tB = __builtin_fmaf(ea, sa[r], tB);
        const bool db = (((mhi >> (8*r)) & 0xffu) != 0u) || (causal && (r + 4 > rel));
        const float eb = db ? 0.f : exp2g(sb[r]);
        lB += eb; tB = __builtin_fmaf(eb, sb[r], tB);
      }
    }
    if (j0c <= imaxA){
      f32x4 sa = __builtin_amdgcn_mfma_f32_16x16x32_bf16(ka0, qfA0, zero4, 0, 0, 0);
      sa       = __builtin_amdgcn_mfma_f32_16x16x32_bf16(ka1, qfA1, sa, 0, 0, 0);
      f32x4 sb = __builtin_amdgcn_mfma_f32_16x16x32_bf16(kb0, qfA0, zero4, 0, 0, 0);
      sb       = __builtin_amdgcn_mfma_f32_16x16x32_bf16(kb1, qfA1, sb, 0, 0, 0);
      const int rel = irowA - jbase;
      #pragma unroll
      for (int r = 0; r < 4; ++r){
        const bool da = (((mlo >> (8*r)) & 0xffu) != 0u) || (causal && (r > rel));
        const float ea = da ? 0.f : exp2g(sa[r]);
        lA += ea; tA = __builtin_fmaf(ea, sa[r], tA);
        const bool db = (((mhi >> (8*r)) & 0xffu) != 0u) || (causal && (r + 4 > rel));
        const float eb = db ? 0.f : exp2g(sb[r]);
        lA += eb; tA = __builtin_fmaf(eb, sb[r], tA);
      }
    }
  }

  // ---- reduce over quads (lane already holds full per-row partial) ----
  #pragma unroll
  for (int off = 16; off < 64; off <<= 1){
    lA += __shfl_xor(lA, off);  tA += __shfl_xor(tA, off);
    lB += __shfl_xor(lB, off);  tB += __shfl_xor(tB, off);
  }
  if (lane < 16){
    lsum[wv][l15]      = lA;  tsum[wv][l15]      = tA;
    lsum[wv][16 + l15] = lB;  tsum[wv][16 + l15] = tB;
  }
  __syncthreads();
  if (tid < 32){
    float l = lsum[0][tid] + lsum[1][tid] + lsum[2][tid] + lsum[3][tid];
    float t = (tsum[0][tid] + tsum[1][tid] + tsum[2][tid] + tsum[3][tid]) * 0.69314718f;
    const int i0t = (tid < 16) ? iA : iB;
    const int row = i0t + (tid & 15);
    int qm = maskQ[b * L_ + row];
    float rc  = (qm != 0) ? 0.f : (1.f / l);
    float ent = (qm != 0) ? 0.f : (__logf(l) - t / l);
    recipS[tid] = rc;
    outEnt[(size_t)bh * L_ + row] = ent;
  }
  __syncthreads();

  const float rqA = recipS[l15];
  const float rqB = recipS[16 + l15];

  // ================= SWEEP 2: A out + PV for both tiles (barrier-free) =================
  f32x4 uaccA[4], uaccB[4];
  #pragma unroll
  for (int et = 0; et < 4; ++et){ uaccA[et] = (f32x4)0.f; uaccB[et] = (f32x4)0.f; }

  for (int sp = 0; sp < nsup; ++sp){
    const int j0c = (sp << 7) + (wv << 5);
    if (j0c > imaxB) break;   // monotone in sp; uniform per wave

    // ---- stage this wave's V[j0c..j0c+32][:] -> vstage [e][j] bf16 pairs, granule-rotated ----
    // wave-private: jp = tid>>2 spans [wv*16, wv*16+16) -> j in [wv*32, wv*32+32)
    {
      const int jp = tid >> 2;
      const int a  = tid & 3;
      const int e0 = a << 4;
      const u16* v0p = Vbh + (size_t)((sp << 7) + 2 * jp) * rstride + e0;
      const u16* v1p = v0p + rstride;
      u32x4 xa = *(const u32x4*)(v0p);       // row 2jp,   e0..e0+7  (u16 pairs)
      u32x4 xb = *(const u32x4*)(v0p + 8);   // row 2jp,   e0+8..15
      u32x4 ya = *(const u32x4*)(v1p);       // row 2jp+1, e0..e0+7
      u32x4 yb = *(const u32x4*)(v1p + 8);   // row 2jp+1, e0+8..15
      const int colsw = ((((jp >> 2) + (a << 2)) & 15) << 2) | (jp & 3);
      u32* vsw = (u32*)vstage;
      #pragma unroll
      for (int m = 0; m < 4; ++m){
        // u32 at [e][colsw] = {bf16 V[2jp][e] (lo), bf16 V[2jp+1][e] (hi)}
        vsw[(e0 + 2*m        ) * (VSTRIDE/2) + colsw] = __builtin_amdgcn_perm(ya[m], xa[m], 0x05040100u);
        vsw[(e0 + 2*m + 1    ) * (VSTRIDE/2) + colsw] = __builtin_amdgcn_perm(ya[m], xa[m], 0x07060302u);
        vsw[(e0 + 8 + 2*m    ) * (VSTRIDE/2) + colsw] = __builtin_amdgcn_perm(yb[m], xb[m], 0x05040100u);
        vsw[(e0 + 8 + 2*m + 1) * (VSTRIDE/2) + colsw] = __builtin_amdgcn_perm(yb[m], xb[m], 0x07060302u);
      }
    }

    const u16* krow = Kbh + (size_t)(j0c + permrow) * rstride + quad * 8;
    const s16x8 ka0 = *(const s16x8*)(krow);
    const s16x8 ka1 = *(const s16x8*)(krow + 32);
    const s16x8 kb0 = *(const s16x8*)(krow + 4 * rstride);
    const s16x8 kb1 = *(const s16x8*)(krow + 4 * rstride + 32);
    const int jbase = j0c + (quad << 3);
    const u64 mk8 = *(const u64*)(mkb + jbase);
    const u32 mlo = (u32)mk8;
    const u32 mhi = (u32)(mk8 >> 32);

    // ---- tile B ----
    {
      f32x4 sa = __builtin_amdgcn_mfma_f32_16x16x32_bf16(ka0, qfB0, zero4, 0, 0, 0);
      sa       = __builtin_amdgcn_mfma_f32_16x16x32_bf16(ka1, qfB1, sa, 0, 0, 0);
      f32x4 sb = __builtin_amdgcn_mfma_f32_16x16x32_bf16(kb0, qfB0, zero4, 0, 0, 0);
      sb       = __builtin_amdgcn_mfma_f32_16x16x32_bf16(kb1, qfB1, sb, 0, 0, 0);
      const int rel = irowB - jbase;
      f32x4 ea, eb;
      #pragma unroll
      for (int r = 0; r < 4; ++r){
        const bool da = (((mlo >> (8*r)) & 0xffu) != 0u) || (causal && (r > rel));
        ea[r] = da ? 0.f : exp2g(sa[r]);
        const bool db = (((mhi >> (8*r)) & 0xffu) != 0u) || (causal && (r + 4 > rel));
        eb[r] = db ? 0.f : exp2g(sb[r]);
      }
      *(f32x4*)(outArowB + (size_t)l15 * S_ + jbase)     = ea * rqB;
      *(f32x4*)(outArowB + (size_t)l15 * S_ + jbase + 4) = eb * rqB;
      const s16x8 pf = pack8(ea, eb);   // direct A-operand: j = quad*8 + {0..7}
      #pragma unroll
      for (int et = 0; et < 4; ++et){
        const int gq = ((wv << 2) + quad + (et << 2)) & 15;
        const s16x8 vf = *(const s16x8*)(vstage + (et * 16 + l15) * VSTRIDE + gq * 8);
        uaccB[et] = __builtin_amdgcn_mfma_f32_16x16x32_bf16(pf, vf, uaccB[et], 0, 0, 0);
      }
    }

    // ---- tile A ----
    if (j0c <= imaxA){
      f32x4 sa = __builtin_amdgcn_mfma_f32_16x16x32_bf16(ka0, qfA0, zero4, 0, 0, 0);
      sa       = __builtin_amdgcn_mfma_f32_16x16x32_bf16(ka1, qfA1, sa, 0, 0, 0);
      f32x4 sb = __builtin_amdgcn_mfma_f32_16x16x32_bf16(kb0, qfA0, zero4, 0, 0, 0);
      sb       = __builtin_amdgcn_mfma_f32_16x16x32_bf16(kb1, qfA1, sb, 0, 0, 0);
      const int rel = irowA - jbase;
      f32x4 ea, eb;
      #pragma unroll
      for (int r = 0; r < 4; ++r){
        const bool da = (((mlo >> (8*r)) & 0xffu) != 0u) || (causal && (r > rel));
        ea[r] = da ? 0.f : exp2g(sa[r]);
        const bool db = (((mhi >> (8*r)) & 0xffu) != 0u) || (causal && (r + 4 > rel));
        eb[r] = db ? 0.f : exp2g(sb[r]);
      }
      *(f32x4*)(outArowA + (size_t)l15 * S_ + jbase)     = ea * rqA;
      *(f32x4*)(outArowA + (size_t)l15 * S_ + jbase + 4) = eb * rqA;
      const s16x8 pf = pack8(ea, eb);
      #pragma unroll
      for (int et = 0; et < 4; ++et){
        const int gq = ((wv << 2) + quad + (et << 2)) & 15;
        const s16x8 vf = *(const s16x8*)(vstage + (et * 16 + l15) * VSTRIDE + gq * 8);
        uaccA[et] = __builtin_amdgcn_mfma_f32_16x16x32_bf16(pf, vf, uaccA[et], 0, 0, 0);
      }
    }
  }

  // ================= epilogue: V outputs for both tiles =================
  float* Ubuf = (float*)vstage;
  __syncthreads();
  #pragma unroll
  for (int et = 0; et < 4; ++et)
    #pragma unroll
    for (int r = 0; r < 4; ++r)
      Ubuf[(wv * 16 + (quad << 2) + r) * 64 + et * 16 + l15] = uaccA[et][r];
  __syncthreads();
  {
    const int i  = tid >> 4;
    const int e4 = (tid & 15) << 2;
    f32x4 s0 = *(const f32x4*)(Ubuf + (0 * 16 + i) * 64 + e4);
    f32x4 s1 = *(const f32x4*)(Ubuf + (1 * 16 + i) * 64 + e4);
    f32x4 s2 = *(const f32x4*)(Ubuf + (2 * 16 + i) * 64 + e4);
    f32x4 s3 = *(const f32x4*)(Ubuf + (3 * 16 + i) * 64 + e4);
    f32x4 vout = (s0 + s1 + s2 + s3) * recipS[i];
    *(f32x4*)(outV + (((size_t)(b * L_ + iA + i)) * H_ + h) * E_ + e4) = vout;
  }
  __syncthreads();
  #pragma unroll
  for (int et = 0; et < 4; ++et)
    #pragma unroll
    for (int r = 0; r < 4; ++r)
      Ubuf[(wv * 16 + (quad << 2) + r) * 64 + et * 16 + l15] = uaccB[et][r];
  __syncthreads();
  {
    const int i  = tid >> 4;
    const int e4 = (tid & 15) << 2;
    f32x4 s0 = *(const f32x4*)(Ubuf + (0 * 16 + i) * 64 + e4);
    f32x4 s1 = *(const f32x4*)(Ubuf + (1 * 16 + i) * 64 + e4);
    f32x4 s2 = *(const f32x4*)(Ubuf + (2 * 16 + i) * 64 + e4);
    f32x4 s3 = *(const f32x4*)(Ubuf + (3 * 16 + i) * 64 + e4);
    f32x4 vout = (s0 + s1 + s2 + s3) * recipS[16 + i];
    *(f32x4*)(outV + (((size_t)(b * L_ + iB + i)) * H_ + h) * E_ + e4) = vout;
  }
}

extern "C" void kernel_launch(void* const* d_in, const int* in_sizes, int n_in,
                              void* d_out, int out_size, void* d_ws, size_t ws_size,
                              hipStream_t stream){
  const float* Q  = (const float*)d_in[0];
  const float* K  = (const float*)d_in[1];
  const float* V  = (const float*)d_in[2];
  const int* mk   = (const int*)d_in[3];
  const int* mq   = (const int*)d_in[4];
  const int* cm   = (const int*)d_in[6];

  float* outV   = (float*)d_out;
  float* outA   = outV + (size_t)B_ * L_ * H_ * E_;
  float* outEnt = outA + (size_t)B_ * H_ * L_ * S_;

  // workspace: Kb (4MB) + Vb (4MB) bf16
  u16* Kb = (u16*)d_ws;
  u16* Vb = Kb + NKV;

  cast_kv_kernel<<<dim3(NKV / (256 * 8)), 256, 0, stream>>>(K, V, Kb, Vb);
  attn_kernel<<<dim3(1024), 256, 0, stream>>>(Q, Kb, Vb, mk, mq, cm, outV, outA, outEnt);
}